// Round 6
// baseline (102.570 us; speedup 1.0000x reference)
//
#include <hip/hip_runtime.h>

#define BB   128        // batch
#define TT   4096       // time
#define NSH  257        // shifts -128..+128 -> j = 0..256
#define PAD  128
#define LTOT 4352.0f    // padded length
#define TC   2048       // t per half-row chunk
#define PPW  (TC + 256) // 2304 pp window floats per chunk
#define PRW  264        // pair_ws floats per row (257 cov + 4 stats, padded)

__device__ __forceinline__ float wave_sum(float v) {
    #pragma unroll
    for (int m = 32; m; m >>= 1) v += __shfl_xor(v, m, 64);
    return v;
}

// One dispatch, 257 blocks (all co-resident: 16 waves/block, 2 blocks/CU).
//   bid 0                  : finalizer — spin on 128 row flags, sum, write out.
//   bid 1..256 (w=bid-1)   : half-row worker, row b=w>>1, chunk c=w&1.
//       c==0: publish chunk partials (cov[257]+stats[4]) + release flag.
//       c==1: compute own chunk, spin for partner, combine, finalize row,
//             publish loss_b/128 + release flag.
// All cross-block handoff via agent-scope atomics (cross-XCD safe).
// Flags start as 0xAA poison != 1, so no zero-init dispatch needed.
extern "C" __global__ __launch_bounds__(1024)
void k_all(const float* __restrict__ preds, const float* __restrict__ labels,
           float* __restrict__ pair_ws, unsigned* __restrict__ pair_flag,
           float* __restrict__ val_ws, unsigned* __restrict__ flag_ws,
           float* __restrict__ out) {
    const int bid = blockIdx.x;
    const int tid = threadIdx.x;
    const int l   = tid & 63;
    const int wv  = tid >> 6;            // 16 waves

    if (bid == 0) {
        // ---- finalizer: one wave polls 2 row-flags/lane, then sums ----
        if (wv != 0) return;
        const int r0 = 2 * l, r1 = r0 + 1;
        for (;;) {
            unsigned f0 = __hip_atomic_load(&flag_ws[r0], __ATOMIC_RELAXED, __HIP_MEMORY_SCOPE_AGENT);
            unsigned f1 = __hip_atomic_load(&flag_ws[r1], __ATOMIC_RELAXED, __HIP_MEMORY_SCOPE_AGENT);
            if (__all((f0 == 1u) && (f1 == 1u))) break;
        }
        __builtin_amdgcn_fence(__ATOMIC_ACQUIRE, "agent");
        float v = __hip_atomic_load(&val_ws[r0], __ATOMIC_RELAXED, __HIP_MEMORY_SCOPE_AGENT)
                + __hip_atomic_load(&val_ws[r1], __ATOMIC_RELAXED, __HIP_MEMORY_SCOPE_AGENT);
        v = wave_sum(v);
        if (l == 0) out[0] = v;
        return;
    }

    __shared__ __align__(16) float pp_s[PPW];   // P[t0+v], P[x] = preds[x-128] zero-padded
    __shared__ __align__(16) float lab_s[TC];
    __shared__ float cov_s[NSH];
    __shared__ float st_s[4];

    const int w  = bid - 1;
    const int b  = w >> 1;
    const int c  = w & 1;
    const int t0 = c * TC;
    const float* pr = preds  + b * TT;
    const float* lr = labels + b * TT;

    // ---- stage (float4; t0-PAD is a multiple of 4, so each 16B chunk is
    //      either fully in-range or fully zero) ----
    {
        const float4 zero = {0.f, 0.f, 0.f, 0.f};
        if (tid < PPW / 4) {                      // 576 float4
            int g = t0 - PAD + 4 * tid;
            *reinterpret_cast<float4*>(&pp_s[4 * tid]) =
                (g >= 0 && g + 3 < TT) ? *reinterpret_cast<const float4*>(pr + g) : zero;
        }
        if (tid < TC / 4)                         // 512 float4
            *reinterpret_cast<float4*>(&lab_s[4 * tid]) =
                *reinterpret_cast<const float4*>(lr + t0 + 4 * tid);
        if (tid < NSH) cov_s[tid] = 0.0f;
        if (tid < 4)   st_s[tid]  = 0.0f;
    }
    __syncthreads();

    // ---- sliding window: lane = 4 consecutive shifts, wave = 128-t slice ----
    const int tq0  = wv * (TC / 16);     // 128 t per wave
    const int boff = 256 - 4 * l;

    float4 prev = *reinterpret_cast<const float4*>(&pp_s[tq0 + boff - 4]);
    float a0 = 0.f, a1 = 0.f, a2 = 0.f, a3 = 0.f;

    #pragma unroll 8
    for (int tq = tq0; tq < tq0 + TC / 16; tq += 4) {   // 32 iters
        const float4 lab = *reinterpret_cast<const float4*>(&lab_s[tq]);        // broadcast
        const float4 cur = *reinterpret_cast<const float4*>(&pp_s[tq + boff]);  // conflict-free b128
        a0 += lab.x * cur.x;  a0 += lab.y * cur.y;  a0 += lab.z * cur.z;  a0 += lab.w * cur.w;
        a1 += lab.x * prev.w; a1 += lab.y * cur.x;  a1 += lab.z * cur.y;  a1 += lab.w * cur.z;
        a2 += lab.x * prev.z; a2 += lab.y * prev.w; a2 += lab.z * cur.x;  a2 += lab.w * cur.y;
        a3 += lab.x * prev.y; a3 += lab.y * prev.z; a3 += lab.z * prev.w; a3 += lab.w * cur.x;
        prev = cur;
    }
    atomicAdd(&cov_s[4 * l + 0], a0);
    atomicAdd(&cov_s[4 * l + 1], a1);
    atomicAdd(&cov_s[4 * l + 2], a2);
    atomicAdd(&cov_s[4 * l + 3], a3);

    // ---- shift j=256 dot + chunk stats (2 elems/thread) ----
    {
        float e = 0.f, sp = 0.f, spp = 0.f, sl = 0.f, sll = 0.f;
        #pragma unroll
        for (int k = 0; k < 2; ++k) {
            int v    = tid + k * 1024;
            float pv = pp_s[v];          // P[t0+v]       (j=256 term)
            float lv = lab_s[v];
            float pc = pp_s[v + PAD];    // preds[t0+v]   (stats)
            e  += lv * pv;
            sp += pc; spp += pc * pc;
            sl += lv; sll += lv * lv;
        }
        e  = wave_sum(e);
        sp = wave_sum(sp); spp = wave_sum(spp);
        sl = wave_sum(sl); sll = wave_sum(sll);
        if (l == 0) {
            atomicAdd(&cov_s[256], e);
            atomicAdd(&st_s[0], sp); atomicAdd(&st_s[1], spp);
            atomicAdd(&st_s[2], sl); atomicAdd(&st_s[3], sll);
        }
    }
    __syncthreads();

    float* pws = pair_ws + b * PRW;

    if (c == 0) {
        // ---- publish chunk partials to partner ----
        if (tid < NSH)
            __hip_atomic_store(&pws[tid], cov_s[tid], __ATOMIC_RELAXED, __HIP_MEMORY_SCOPE_AGENT);
        if (tid < 4)
            __hip_atomic_store(&pws[NSH + tid], st_s[tid], __ATOMIC_RELAXED, __HIP_MEMORY_SCOPE_AGENT);
        __syncthreads();   // per-wave vmcnt(0) drain -> stores complete
        if (tid == 0)
            __hip_atomic_store(&pair_flag[b], 1u, __ATOMIC_RELEASE, __HIP_MEMORY_SCOPE_AGENT);
        return;
    }

    // ---- c==1: wait for partner (overlapped with own compute above) ----
    if (tid == 0) {
        while (__hip_atomic_load(&pair_flag[b], __ATOMIC_RELAXED, __HIP_MEMORY_SCOPE_AGENT) != 1u) {}
    }
    __syncthreads();
    __builtin_amdgcn_fence(__ATOMIC_ACQUIRE, "agent");
    if (tid < NSH)
        cov_s[tid] += __hip_atomic_load(&pws[tid], __ATOMIC_RELAXED, __HIP_MEMORY_SCOPE_AGENT);
    if (tid < 4)
        st_s[tid]  += __hip_atomic_load(&pws[NSH + tid], __ATOMIC_RELAXED, __HIP_MEMORY_SCOPE_AGENT);
    __syncthreads();

    // ---- finalize row: corr -> max -> publish ----
    if (wv == 0) {
        float Sp = st_s[0], Spp = st_s[1], Sl = st_s[2], Sll = st_s[3];
        float xn2 = Spp - Sp * Sp / LTOT;
        float yn2 = Sll - Sl * Sl / LTOT;
        float inv = rsqrtf(xn2 * yn2);
        float cst = Sp * Sl / LTOT;
        float mx = -1e30f;
        for (int j = l; j < NSH; j += 64)
            mx = fmaxf(mx, (cov_s[j] - cst) * inv);
        #pragma unroll
        for (int m = 32; m; m >>= 1) mx = fmaxf(mx, __shfl_xor(mx, m, 64));
        if (l == 0) {
            __hip_atomic_store(&val_ws[b], (1.0f - mx) * (1.0f / BB),
                               __ATOMIC_RELAXED, __HIP_MEMORY_SCOPE_AGENT);
            __hip_atomic_store(&flag_ws[b], 1u,
                               __ATOMIC_RELEASE, __HIP_MEMORY_SCOPE_AGENT);
        }
    }
}

extern "C" void kernel_launch(void* const* d_in, const int* in_sizes, int n_in,
                              void* d_out, int out_size, void* d_ws, size_t ws_size,
                              hipStream_t stream) {
    const float* preds  = (const float*)d_in[0];
    const float* labels = (const float*)d_in[1];
    float*    out       = (float*)d_out;
    float*    pair_ws   = (float*)d_ws;                    // [BB][PRW]
    unsigned* pair_flag = (unsigned*)(pair_ws + BB * PRW); // [BB], poison != 1
    float*    val_ws    = (float*)(pair_flag + BB);        // [BB]
    unsigned* flag_ws   = (unsigned*)(val_ws + BB);        // [BB], poison != 1

    hipLaunchKernelGGL(k_all, dim3(2 * BB + 1), dim3(1024), 0, stream,
                       preds, labels, pair_ws, pair_flag, val_ws, flag_ws, out);
}

// Round 7
// 74.667 us; speedup vs baseline: 1.3737x; 1.3737x over previous
//
#include <hip/hip_runtime.h>

#define BB   128        // batch
#define TT   4096       // time
#define NSH  257        // shifts -128..+128 -> j = 0..256
#define PAD  128
#define LTOT 4352.0f    // padded length
#define PPW  (TT + 256) // 4352 pp window floats (full row)
// ws counter starts at harness poison 0xAA bytes (documented: re-poisoned before
// every timed launch). After 128 increments the last worker sees old == POISON+127.
#define POISON 0xAAAAAAAAu

__device__ __forceinline__ float wave_sum(float v) {
    #pragma unroll
    for (int m = 32; m; m >>= 1) v += __shfl_xor(v, m, 64);
    return v;
}

// One dispatch, 128 blocks (one full row each), NO spinning:
// each block computes its row loss, publishes val_ws[b] (agent relaxed),
// then release-fetch_adds a counter; the LAST block (old == POISON+127)
// acquire-fences and sums all 128 values -> out. Single sync layer.
extern "C" __global__ __launch_bounds__(1024)
void k_all(const float* __restrict__ preds, const float* __restrict__ labels,
           float* __restrict__ val_ws, unsigned* __restrict__ counter,
           float* __restrict__ out) {
    __shared__ __align__(16) float pp_s[PPW];   // P[v] = preds[v-128], zero-padded
    __shared__ __align__(16) float lab_s[TT];
    __shared__ float cov_s[NSH];
    __shared__ float st_s[4];

    const int b   = blockIdx.x;
    const int tid = threadIdx.x;
    const int l   = tid & 63;
    const int wv  = tid >> 6;            // 16 waves

    const float* pr = preds  + b * TT;
    const float* lr = labels + b * TT;

    // ---- stage full row, float4 (edge windows are fully in- or out-of-range
    //      since -PAD is a multiple of 4) ----
    {
        const float4 zero = {0.f, 0.f, 0.f, 0.f};
        #pragma unroll
        for (int i = tid; i < PPW / 4; i += 1024) {      // 1088 float4
            int g = 4 * i - PAD;
            *reinterpret_cast<float4*>(&pp_s[4 * i]) =
                (g >= 0 && g + 3 < TT) ? *reinterpret_cast<const float4*>(pr + g) : zero;
        }
        *reinterpret_cast<float4*>(&lab_s[4 * tid]) =     // 1024 float4
            *reinterpret_cast<const float4*>(lr + 4 * tid);
        if (tid < NSH) cov_s[tid] = 0.0f;
        if (tid < 4)   st_s[tid]  = 0.0f;
    }
    __syncthreads();

    // ---- sliding window: lane = 4 consecutive shifts, wave = 256-t slice ----
    const int tq0  = wv * (TT / 16);     // 256 t per wave
    const int boff = 256 - 4 * l;

    float4 prev = *reinterpret_cast<const float4*>(&pp_s[tq0 + boff - 4]);
    float a0 = 0.f, a1 = 0.f, a2 = 0.f, a3 = 0.f;

    #pragma unroll 8
    for (int tq = tq0; tq < tq0 + TT / 16; tq += 4) {   // 64 iters
        const float4 lab = *reinterpret_cast<const float4*>(&lab_s[tq]);        // broadcast
        const float4 cur = *reinterpret_cast<const float4*>(&pp_s[tq + boff]);  // conflict-free b128
        a0 += lab.x * cur.x;  a0 += lab.y * cur.y;  a0 += lab.z * cur.z;  a0 += lab.w * cur.w;
        a1 += lab.x * prev.w; a1 += lab.y * cur.x;  a1 += lab.z * cur.y;  a1 += lab.w * cur.z;
        a2 += lab.x * prev.z; a2 += lab.y * prev.w; a2 += lab.z * cur.x;  a2 += lab.w * cur.y;
        a3 += lab.x * prev.y; a3 += lab.y * prev.z; a3 += lab.z * prev.w; a3 += lab.w * cur.x;
        prev = cur;
    }
    atomicAdd(&cov_s[4 * l + 0], a0);
    atomicAdd(&cov_s[4 * l + 1], a1);
    atomicAdd(&cov_s[4 * l + 2], a2);
    atomicAdd(&cov_s[4 * l + 3], a3);

    // ---- shift j=256 dot + full-row stats (4 elems/thread) ----
    {
        float e = 0.f, sp = 0.f, spp = 0.f, sl = 0.f, sll = 0.f;
        #pragma unroll
        for (int k = 0; k < 4; ++k) {
            int v    = tid + k * 1024;
            float pv = pp_s[v];          // P[v]        (j=256 term)
            float lv = lab_s[v];
            float pc = pp_s[v + PAD];    // preds[v]    (stats)
            e  += lv * pv;
            sp += pc; spp += pc * pc;
            sl += lv; sll += lv * lv;
        }
        e  = wave_sum(e);
        sp = wave_sum(sp); spp = wave_sum(spp);
        sl = wave_sum(sl); sll = wave_sum(sll);
        if (l == 0) {
            atomicAdd(&cov_s[256], e);
            atomicAdd(&st_s[0], sp); atomicAdd(&st_s[1], spp);
            atomicAdd(&st_s[2], sl); atomicAdd(&st_s[3], sll);
        }
    }
    __syncthreads();

    // ---- finalize row in wave 0: corr -> max -> publish; last block sums ----
    if (wv != 0) return;

    float Sp = st_s[0], Spp = st_s[1], Sl = st_s[2], Sll = st_s[3];
    float xn2 = Spp - Sp * Sp / LTOT;
    float yn2 = Sll - Sl * Sl / LTOT;
    float inv = rsqrtf(xn2 * yn2);
    float cst = Sp * Sl / LTOT;
    float mx = -1e30f;
    for (int j = l; j < NSH; j += 64)
        mx = fmaxf(mx, (cov_s[j] - cst) * inv);
    #pragma unroll
    for (int m = 32; m; m >>= 1) mx = fmaxf(mx, __shfl_xor(mx, m, 64));

    unsigned old = 0;
    if (l == 0) {
        __hip_atomic_store(&val_ws[b], (1.0f - mx) * (1.0f / BB),
                           __ATOMIC_RELAXED, __HIP_MEMORY_SCOPE_AGENT);
        old = __hip_atomic_fetch_add(counter, 1u,
                                     __ATOMIC_ACQ_REL, __HIP_MEMORY_SCOPE_AGENT);
    }
    old = __shfl(old, 0, 64);
    if (old != POISON + 127u) return;    // not the last block

    // ---- last block: all 128 row losses are visible; sum and write out ----
    __builtin_amdgcn_fence(__ATOMIC_ACQUIRE, "agent");
    float v = __hip_atomic_load(&val_ws[2 * l],     __ATOMIC_RELAXED, __HIP_MEMORY_SCOPE_AGENT)
            + __hip_atomic_load(&val_ws[2 * l + 1], __ATOMIC_RELAXED, __HIP_MEMORY_SCOPE_AGENT);
    v = wave_sum(v);
    if (l == 0) out[0] = v;
}

extern "C" void kernel_launch(void* const* d_in, const int* in_sizes, int n_in,
                              void* d_out, int out_size, void* d_ws, size_t ws_size,
                              hipStream_t stream) {
    const float* preds  = (const float*)d_in[0];
    const float* labels = (const float*)d_in[1];
    float*    out     = (float*)d_out;
    float*    val_ws  = (float*)d_ws;                  // [BB]
    unsigned* counter = (unsigned*)(val_ws + 256);     // separate cache line, poison-init

    hipLaunchKernelGGL(k_all, dim3(BB), dim3(1024), 0, stream,
                       preds, labels, val_ws, counter, out);
}